// Round 1
// 1398.858 us; speedup vs baseline: 1.0368x; 1.0368x over previous
//
#include <hip/hip_runtime.h>
#include <hip/hip_bf16.h>

// Problem constants (fixed by the reference)
#define EPSF 1e-8f
constexpr int M_ = 8, N_ = 100000, D_ = 256, H_ = 256;
constexpr int NP_ = N_ / 2;   // 50000 n-pairs

typedef short  short8  __attribute__((ext_vector_type(8)));   // bf16x8 MFMA frag (4 VGPRs)
typedef short  short4_ __attribute__((ext_vector_type(4)));
typedef float  float4_ __attribute__((ext_vector_type(4)));

__device__ __forceinline__ short bf16_rn(float x) {
  union { float f; unsigned u; } v; v.f = x;
  unsigned r = v.u + 0x7FFFu + ((v.u >> 16) & 1u);   // round-to-nearest-even
  return (short)(r >> 16);
}

// tanh(x) = (e^{2x}-1)/(e^{2x}+1); clamp so e^{2x} stays finite.
// v_exp_f32 + v_rcp_f32: ~6 VALU vs ~28 for libm tanhf. |err| ~1e-6.
__device__ __forceinline__ float fast_tanh(float x) {
  const float xc = fminf(fmaxf(x, -9.0f), 9.0f);
  const float e2 = __builtin_amdgcn_exp2f(xc * 2.8853900817779268f);  // e^{2x}
  return (e2 - 1.0f) * __builtin_amdgcn_rcpf(e2 + 1.0f);
}

// LDS strides (elements):
//   xb (bf16): 264  -> row byte-stride 528; A-frag b128 reads spread 8 lanes/bank-quad
//   xf (f32) : 257  -> (r + j) % 32 banks, conflict-free scalar access
//   tg (f32) : 260  -> 16B-aligned float4 stores
#define XB_S 264
#define XF_S 257
#define TG_S 260

__global__ __launch_bounds__(256, 2) void fused_hete(
    const int* __restrict__ nodes, const float* __restrict__ homo,
    const float* __restrict__ W, const float* __restrict__ bias,
    const float* __restrict__ oute, float* __restrict__ out)
{
  __shared__ __align__(16) short xb[16 * XB_S];
  __shared__ __align__(16) float xf[16 * XF_S];
  __shared__ __align__(16) float tg[2 * TG_S];
  __shared__ __align__(16) float rnum[4][16];
  __shared__ __align__(16) float rhn[4][16];
  __shared__ float tn_s[2];

  const int t    = threadIdx.x;
  const int wave = t >> 6, lane = t & 63;
  const int quad = lane >> 4, l16 = lane & 15;

  // ---- Preload W as B-fragments in registers (per wave: cols wave*64 .. +63) ----
  short8 wf[4][8];
  float  bcol[4];
  #pragma unroll
  for (int tt = 0; tt < 4; ++tt) {
    const int col = wave * 64 + tt * 16 + l16;
    bcol[tt] = bias[col];
    #pragma unroll
    for (int k0 = 0; k0 < 8; ++k0) {
      const float* wp = W + (size_t)col * D_ + k0 * 32 + quad * 8;
      short8 f;
      #pragma unroll
      for (int j = 0; j < 8; ++j) f[j] = bf16_rn(wp[j]);
      wf[tt][k0] = f;
    }
  }

  // ---- staging geometry (16 rows = 2n x 8m, 16 threads/row) ----
  const int sr = t >> 4, sc = t & 15;          // row / col-group
  const int sm = sr & 7, sln = sr >> 3;        // row sr = sln*8 + sm
  const float* hbase = homo + ((size_t)sm * N_ + sln) * D_ + sc * 4;
  const int ln2 = t >> 6;                      // gather half (valid for t<128)
  const int c2  = t & 63;

  // ---- prefetch registers (T14 async-STAGE split) ----
  float4 hreg[4];                              // next homo tile (this thread's 16 floats)
  float4 treg = {0.f, 0.f, 0.f, 0.f};          // next gather row chunk
  int    nidx = 0;                             // node idx prefetched TWO tiles ahead

  const int p0 = blockIdx.x;
  {
    // prologue: load tile p0; prefetch node index for p0+grid
    const float* src = hbase + (size_t)(p0 * 2) * D_;
    #pragma unroll
    for (int i = 0; i < 4; ++i) hreg[i] = *(const float4*)(src + i * 64);
    if (t < 128) {
      const int nd = nodes[p0 * 2 + ln2];
      treg = *(const float4*)(oute + (size_t)nd * H_ + c2 * 4);
      const int p1 = p0 + (int)gridDim.x;
      if (p1 < NP_) nidx = nodes[p1 * 2 + ln2];
    }
  }

  for (int pair = p0; pair < NP_; pair += gridDim.x) {
    const int n0 = pair * 2;

    // ---- write prefetched tile regs -> LDS (bf16 for MFMA + f32 for epilogue) ----
    #pragma unroll
    for (int i = 0; i < 4; ++i) {
      const int d = i * 64 + sc * 4;
      const float4 v = hreg[i];
      float* xfr = &xf[sr * XF_S + d];
      xfr[0] = v.x; xfr[1] = v.y; xfr[2] = v.z; xfr[3] = v.w;
      short4_ s4;
      s4[0] = bf16_rn(v.x); s4[1] = bf16_rn(v.y); s4[2] = bf16_rn(v.z); s4[3] = bf16_rn(v.w);
      *(short4_*)&xb[sr * XB_S + d] = s4;      // 8B-aligned (d%4==0)
    }
    if (t < 128) {
      const float4 v = treg;
      float* tp = &tg[ln2 * TG_S + c2 * 4];
      tp[0] = v.x; tp[1] = v.y; tp[2] = v.z; tp[3] = v.w;
      float sq = v.x * v.x + v.y * v.y + v.z * v.z + v.w * v.w;
      #pragma unroll
      for (int off = 32; off; off >>= 1) sq += __shfl_down(sq, off);
      if (c2 == 0) tn_s[ln2] = fmaxf(__builtin_amdgcn_sqrtf(sq), EPSF);
    }

    // ---- issue async prefetch for the NEXT tile (lands during this iter's compute) ----
    const int pnext = pair + (int)gridDim.x;
    if (pnext < NP_) {
      const float* src = hbase + (size_t)(pnext * 2) * D_;
      #pragma unroll
      for (int i = 0; i < 4; ++i) hreg[i] = *(const float4*)(src + i * 64);
      if (t < 128) {
        // nidx was loaded a full iteration ago -> no dependent-gather stall here
        treg = *(const float4*)(oute + (size_t)nidx * H_ + c2 * 4);
        const int pnn = pnext + (int)gridDim.x;
        if (pnn < NP_) nidx = nodes[pnn * 2 + ln2];
      }
    }
    __syncthreads();   // B1: LDS tile ready (prefetch loads stay in flight past here)

    // ---- MFMA: hidden tile 16 rows x 64 cols per wave, K = 256 ----
    float4_ acc[4] = {};
    #pragma unroll
    for (int k0 = 0; k0 < 8; ++k0) {
      const short8 af = *(const short8*)&xb[l16 * XB_S + k0 * 32 + quad * 8];
      #pragma unroll
      for (int tt = 0; tt < 4; ++tt)
        acc[tt] = __builtin_amdgcn_mfma_f32_16x16x32_bf16(af, wf[tt][k0], acc[tt], 0, 0, 0);
    }

    // ---- Epilogue: tanh, partial dot with tgt and ||hidden||^2 ----
    // C-layout: col = lane&15 (+tile), row = quad*4 + e
    const int lnq = quad >> 1;
    float nump[4] = {0.f, 0.f, 0.f, 0.f}, hnp[4] = {0.f, 0.f, 0.f, 0.f};
    #pragma unroll
    for (int tt = 0; tt < 4; ++tt) {
      const float tv = tg[lnq * TG_S + wave * 64 + tt * 16 + l16];
      #pragma unroll
      for (int e = 0; e < 4; ++e) {
        const float h = fast_tanh(acc[tt][e] + bcol[tt]);
        nump[e] += h * tv;
        hnp[e]  += h * h;
      }
    }
    #pragma unroll
    for (int off = 1; off < 16; off <<= 1) {   // reduce across the 16 lanes of each quad
      #pragma unroll
      for (int e = 0; e < 4; ++e) {
        nump[e] += __shfl_xor(nump[e], off);
        hnp[e]  += __shfl_xor(hnp[e], off);
      }
    }
    if (l16 == 0) {
      #pragma unroll
      for (int e = 0; e < 4; ++e) {
        rnum[wave][quad * 4 + e] = nump[e];
        rhn[wave][quad * 4 + e]  = hnp[e];
      }
    }
    __syncthreads();   // B2

    // ---- cos + softmax, computed redundantly per thread (kills 2 barriers) ----
    // All lanes of a wave read identical LDS addresses -> broadcast, no conflicts.
    const int fln = t >> 7, j = t & 127;
    float4_ nm0 = {0,0,0,0}, nm1 = {0,0,0,0}, hq0 = {0,0,0,0}, hq1 = {0,0,0,0};
    #pragma unroll
    for (int w = 0; w < 4; ++w) {
      nm0 += *(const float4_*)&rnum[w][fln * 8];
      nm1 += *(const float4_*)&rnum[w][fln * 8 + 4];
      hq0 += *(const float4_*)&rhn[w][fln * 8];
      hq1 += *(const float4_*)&rhn[w][fln * 8 + 4];
    }
    const float tn = tn_s[fln];
    float cosv[8], mx = -3.0e38f;
    #pragma unroll
    for (int m = 0; m < 8; ++m) {
      const float nm = (m < 4) ? nm0[m] : nm1[m - 4];
      const float hq = (m < 4) ? hq0[m] : hq1[m - 4];
      const float hn = fmaxf(__builtin_amdgcn_sqrtf(hq), EPSF);
      cosv[m] = nm * __builtin_amdgcn_rcpf(hn * tn);
      mx = fmaxf(mx, cosv[m]);
    }
    float att[8], ssum = 0.f;
    #pragma unroll
    for (int m = 0; m < 8; ++m) {
      att[m] = __builtin_amdgcn_exp2f((cosv[m] - mx) * 1.4426950408889634f);
      ssum += att[m];
    }
    const float inv = __builtin_amdgcn_rcpf(ssum);

    // ---- final: out[n][d] = sum_m att[m] * x_fp32[m][n][d] ----
    float s0 = 0.f, s1 = 0.f;
    #pragma unroll
    for (int m = 0; m < 8; ++m) {
      const float a = att[m] * inv;
      s0 += a * xf[(fln * 8 + m) * XF_S + j];
      s1 += a * xf[(fln * 8 + m) * XF_S + j + 128];
    }
    float* op = out + (size_t)(n0 + fln) * D_;
    op[j] = s0; op[j + 128] = s1;
    __syncthreads();   // B_end: protect xf/tg/rnum before next iteration's writes
  }
}

extern "C" void kernel_launch(void* const* d_in, const int* in_sizes, int n_in,
                              void* d_out, int out_size, void* d_ws, size_t ws_size,
                              hipStream_t stream) {
  const int*   nodes = (const int*)d_in[0];
  const float* homo  = (const float*)d_in[1];
  const float* W     = (const float*)d_in[2];
  const float* b     = (const float*)d_in[3];
  const float* oute  = (const float*)d_in[4];
  float* out = (float*)d_out;
  // 1024 blocks: grid-stride over 50000 n-pairs; >=2 blocks/CU resident,
  // 3-4/CU if final VGPR count permits (LDS ~27.6 KB allows 5).
  fused_hete<<<dim3(1024), dim3(256), 0, stream>>>(nodes, homo, W, b, oute, out);
}